// Round 18
// baseline (136.941 us; speedup 1.0000x reference)
//
#include <hip/hip_runtime.h>
#include <hip/hip_bf16.h>

#define B_  4
#define N_  2048
#define E_  256
#define H_  8
#define D_  32
#define QT  32   // q-rows per block
#define KC  64   // keys per chunk
#define HPB 4    // heads per block
#define VTP 72   // V^T row stride (ushorts): 144B
#define PP  72   // P row stride (ushorts)
#define IFP 68   // ab row stride (uints): 272B
#define LOG2E 1.4426950408889634f

typedef __attribute__((ext_vector_type(8))) short bfx8;
typedef __attribute__((ext_vector_type(4))) float fx4;

__device__ __forceinline__ unsigned short f2bf(float f) {
    unsigned int u = __float_as_uint(f);
    u += 0x7fffu + ((u >> 16) & 1u);   // round-to-nearest-even
    return (unsigned short)(u >> 16);
}

__device__ __forceinline__ float bf2f(unsigned short u) {
    return __uint_as_float((unsigned int)u << 16);
}

// pack two f32 -> two bf16 (RNE) in one VALU op: dst = bf16(lo) | bf16(hi)<<16
__device__ __forceinline__ unsigned int cvt_pk_bf16(float lo, float hi) {
    unsigned int r;
    asm("v_cvt_pk_bf16_f32 %0, %1, %2" : "=v"(r) : "v"(lo), "v"(hi));
    return r;
}

// ---------- prep: Wt[n][k] = bf16(W[k][n]) for 6 weight matrices ----------
__global__ __launch_bounds__(256) void prep_w(
    const float* Wa, const float* Wb, const float* Wc,
    const float* Wd, const float* We, const float* Wf,
    unsigned short* Oa, unsigned short* Ob, unsigned short* Oc,
    unsigned short* Od, unsigned short* Oe, unsigned short* Of)
{
    int z = blockIdx.z;
    const float* src = z == 0 ? Wa : z == 1 ? Wb : z == 2 ? Wc
                     : z == 3 ? Wd : z == 4 ? We : Wf;
    unsigned short* dst = z == 0 ? Oa : z == 1 ? Ob : z == 2 ? Oc
                        : z == 3 ? Od : z == 4 ? Oe : Of;
    __shared__ float t[32][33];
    int n0 = blockIdx.x * 32, k0 = blockIdx.y * 32;
    int tx = threadIdx.x & 31, ty = threadIdx.x >> 5;
#pragma unroll
    for (int i = 0; i < 4; i++)
        t[ty + i * 8][tx] = src[(k0 + ty + i * 8) * E_ + n0 + tx];
    __syncthreads();
#pragma unroll
    for (int i = 0; i < 4; i++)
        dst[(n0 + ty + i * 8) * E_ + k0 + tx] = f2bf(t[tx][ty + i * 8]);
}

// ---------- LayerNorm (fp32 in): ONE WAVE per row; 4 rows/block ----------
__global__ __launch_bounds__(256) void ln_kernel(const float* __restrict__ x,
                                                 const float* __restrict__ g,
                                                 const float* __restrict__ be,
                                                 unsigned short* __restrict__ out)
{
    const int w = threadIdx.x >> 6, lane = threadIdx.x & 63;
    const long row = (long)blockIdx.x * 4 + w;
    const float* xr = &x[row * E_];
    float4 v = *(const float4*)&xr[lane * 4];
    float s  = v.x + v.y + v.z + v.w;
    float s2 = v.x * v.x + v.y * v.y + v.z * v.z + v.w * v.w;
#pragma unroll
    for (int off = 32; off; off >>= 1) {
        s  += __shfl_xor(s,  off, 64);
        s2 += __shfl_xor(s2, off, 64);
    }
    float mu  = s * (1.0f / E_);
    float var = s2 * (1.0f / E_) - mu * mu;
    float rstd = rsqrtf(var + 1e-5f);
    float4 gg = *(const float4*)&g[lane * 4];
    float4 bb = *(const float4*)&be[lane * 4];
    float y0 = (v.x - mu) * rstd * gg.x + bb.x;
    float y1 = (v.y - mu) * rstd * gg.y + bb.y;
    float y2 = (v.z - mu) * rstd * gg.z + bb.z;
    float y3 = (v.w - mu) * rstd * gg.w + bb.w;
    uint2 o;
    o.x = cvt_pk_bf16(y0, y1);
    o.y = cvt_pk_bf16(y2, y3);
    *(uint2*)&out[row * E_ + lane * 4] = o;
}

// ---------- LayerNorm (bf16 in): ONE WAVE per row; 4 rows/block ----------
__global__ __launch_bounds__(256) void ln_bf16(const unsigned short* __restrict__ x,
                                               const float* __restrict__ g,
                                               const float* __restrict__ be,
                                               unsigned short* __restrict__ out)
{
    const int w = threadIdx.x >> 6, lane = threadIdx.x & 63;
    const long row = (long)blockIdx.x * 4 + w;
    uint2 u = *(const uint2*)&x[row * E_ + lane * 4];
    float v0 = __uint_as_float(u.x << 16);
    float v1 = __uint_as_float(u.x & 0xffff0000u);
    float v2 = __uint_as_float(u.y << 16);
    float v3 = __uint_as_float(u.y & 0xffff0000u);
    float s  = v0 + v1 + v2 + v3;
    float s2 = v0 * v0 + v1 * v1 + v2 * v2 + v3 * v3;
#pragma unroll
    for (int off = 32; off; off >>= 1) {
        s  += __shfl_xor(s,  off, 64);
        s2 += __shfl_xor(s2, off, 64);
    }
    float mu  = s * (1.0f / E_);
    float var = s2 * (1.0f / E_) - mu * mu;
    float rstd = rsqrtf(var + 1e-5f);
    float4 gg = *(const float4*)&g[lane * 4];
    float4 bb = *(const float4*)&be[lane * 4];
    float y0 = (v0 - mu) * rstd * gg.x + bb.x;
    float y1 = (v1 - mu) * rstd * gg.y + bb.y;
    float y2 = (v2 - mu) * rstd * gg.z + bb.z;
    float y3 = (v3 - mu) * rstd * gg.w + bb.w;
    uint2 o;
    o.x = cvt_pk_bf16(y0, y1);
    o.y = cvt_pk_bf16(y2, y3);
    *(uint2*)&out[row * E_ + lane * 4] = o;
}

// ---------- bf16 MFMA GEMM core: A staged in LDS, B read direct from L2 ------
// C[m][n] = sum_k A[m][k] * Wt[n][k]; C stride = ldC. rbf: residual is bf16.
// B-tile (64x256 = 32KB) is L2-hot (shared by all m-blocks of the column);
// 16 independent 16B loads fully unrolled -> compiler hoists above MFMA chain.
// LDS 33KB -> 3 blocks/CU.
__device__ __forceinline__ void gemm_core(
    const unsigned short* __restrict__ A,
    const unsigned short* __restrict__ Wt,
    const float* __restrict__ bias,
    const void* __restrict__ resid, int rbf,
    void* __restrict__ Cv, int relu, int obf, int m0, int n0, int ldC)
{
    __shared__ unsigned short As[64 * 264];
    int tid = threadIdx.x;

    {   // stage A strip 64x256 (contiguous rows), coalesced 16B/lane
        const unsigned short* Ab = A + (long)m0 * E_;
        bfx8 va[8];
#pragma unroll
        for (int i = 0; i < 8; i++) va[i] = *(const bfx8*)&Ab[(i * 256 + tid) * 8];
#pragma unroll
        for (int i = 0; i < 8; i++) {
            int fo = i * 256 + tid;
            int row = fo >> 5, c8 = fo & 31;
            *(bfx8*)&As[row * 264 + c8 * 8] = va[i];
        }
    }
    __syncthreads();

    int lane = tid & 63, w = tid >> 6;
    int c = lane & 15, g = lane >> 4;
    int wm = (w >> 1) * 32, wn = (w & 1) * 32;
    const unsigned short* Bb0 = Wt + (long)(n0 + wn + c) * E_ + g * 8;
    const unsigned short* Bb1 = Bb0 + 16L * E_;
    fx4 acc[2][2] = {};

#pragma unroll
    for (int ks = 0; ks < 8; ks++) {
        bfx8 b0 = *(const bfx8*)(Bb0 + ks * 32);
        bfx8 b1 = *(const bfx8*)(Bb1 + ks * 32);
        bfx8 a0 = *(const bfx8*)&As[(wm + c)      * 264 + ks * 32 + g * 8];
        bfx8 a1 = *(const bfx8*)&As[(wm + 16 + c) * 264 + ks * 32 + g * 8];
        acc[0][0] = __builtin_amdgcn_mfma_f32_16x16x32_bf16(a0, b0, acc[0][0], 0, 0, 0);
        acc[0][1] = __builtin_amdgcn_mfma_f32_16x16x32_bf16(a0, b1, acc[0][1], 0, 0, 0);
        acc[1][0] = __builtin_amdgcn_mfma_f32_16x16x32_bf16(a1, b0, acc[1][0], 0, 0, 0);
        acc[1][1] = __builtin_amdgcn_mfma_f32_16x16x32_bf16(a1, b1, acc[1][1], 0, 0, 0);
    }

#pragma unroll
    for (int fm = 0; fm < 2; fm++)
#pragma unroll
        for (int r = 0; r < 4; r++) {
            int m = m0 + wm + fm * 16 + g * 4 + r;
#pragma unroll
            for (int fn = 0; fn < 2; fn++) {
                int n = n0 + wn + fn * 16 + c;
                float o = acc[fm][fn][r];
                if (bias)  o += bias[n];
                if (relu)  o = fmaxf(o, 0.f);
                if (resid) {
                    float rv = rbf ? bf2f(((const unsigned short*)resid)[(long)m * ldC + n])
                                   : ((const float*)resid)[(long)m * ldC + n];
                    o += rv;
                }
                if (obf) ((unsigned short*)Cv)[(long)m * ldC + n] = f2bf(o);
                else     ((float*)Cv)[(long)m * ldC + n] = o;
            }
        }
}

__global__ __launch_bounds__(256, 3) void gemm_mfma(
    const unsigned short* __restrict__ A,
    const unsigned short* __restrict__ Wt,
    const float* __restrict__ bias,
    const void* __restrict__ resid, int rbf,
    void* __restrict__ Cv, int relu, int obf)
{
    gemm_core(A, Wt, bias, resid, rbf, Cv, relu, obf,
              blockIdx.x * 64, blockIdx.y * 64, E_);
}

// merged QKV. z==2 computes V^T: Vt[ch][tok] = sum_k Wvt[ch][k]*X[tok][k]
// (roles of A/W swapped; channel-major output, ldC = 8192).
__global__ __launch_bounds__(256, 3) void gemm_qkv(
    const unsigned short* __restrict__ A,
    const unsigned short* __restrict__ Wq, unsigned short* __restrict__ qo,
    const unsigned short* __restrict__ Wk, unsigned short* __restrict__ ko,
    const unsigned short* __restrict__ Wv, unsigned short* __restrict__ vto)
{
    int z = blockIdx.z;
    if (z == 2) {
        gemm_core(Wv, A, nullptr, nullptr, 0, vto, 0, 1,
                  blockIdx.y * 64, blockIdx.x * 64, B_ * N_);
    } else {
        const unsigned short* Wt = z == 0 ? Wq : Wk;
        unsigned short*       Cv = z == 0 ? qo : ko;
        gemm_core(A, Wt, nullptr, nullptr, 0, Cv, 0, 1,
                  blockIdx.x * 64, blockIdx.y * 64, E_);
    }
}

// ---------- MFMA flash attention: QT=32, 4 heads/block, dbuf infl ------------
// (R13/R16 config — best measured 124.6us.) ab plane: uint = bf16(a')|bf16(b)<<16
//   a' = fr*iw1*log2e + ib1*log2e  (dropped -M2 constant cancels exactly)
//   b  = fr*iw2 + ib2
// softmax: s = fma(st, scale2, a'); p = exp2(s); pr = p*b. uint4 reads (16B).
__global__ __launch_bounds__(256, 2) void attn_mfma(
    const unsigned short* __restrict__ q,
    const unsigned short* __restrict__ k,
    const unsigned short* __restrict__ vt,   // [E_][B_*N_] channel-major
    const float* __restrict__ infl,
    const float* __restrict__ iw1p, const float* __restrict__ ib1p,
    const float* __restrict__ iw2p, const float* __restrict__ ib2p,
    unsigned short* __restrict__ out)
{
    const int bx  = blockIdx.x;                 // 512 blocks
    const int xcd = bx & 7;
    const int b   = xcd >> 1;                   // batch
    const int hg  = (xcd & 1) * HPB;            // head-group base
    const int q0  = (bx >> 3) * QT;
    const int tid = threadIdx.x;
    const int h    = tid >> 6;                  // wave id 0..3
    const int head = hg + h;
    const int lane = tid & 63;
    const int c = lane & 15, g = lane >> 4, g4 = g * 4;

    const float iw1e = iw1p[0] * LOG2E, ib1e = ib1p[0] * LOG2E;
    const float iw2 = iw2p[0], ib2 = ib2p[0];
    const float scale2 = 0.17677669529663687f * LOG2E;  // log2e/sqrt(32)

    __shared__ unsigned short vt_lds[HPB][D_][VTP];     // 18432B wave-private
    __shared__ unsigned short p_lds[HPB][QT][PP];       // 18432B wave-private
    __shared__ unsigned int ab_lds[2][QT][IFP];         // 17408B block dbuf

    // Q fragments (2 q-subtiles)
    bfx8 qf0 = *(const bfx8*)&q[((long)(b * N_ + q0 +      c)) * E_ + head * D_ + g * 8];
    bfx8 qf1 = *(const bfx8*)&q[((long)(b * N_ + q0 + 16 + c)) * E_ + head * D_ + g * 8];

    const unsigned short* kbase = &k[((long)(b * N_) + c) * E_ + head * D_ + g * 8];
    // V^T staging coords: row = (lane>>3)+8i (d-channel), keys = (lane&7)*8
    const long MT = (long)B_ * N_;   // 8192
    const int vrow = lane >> 3, vcol = (lane & 7) * 8;
    const unsigned short* vtg = &vt[((long)(head * D_ + vrow)) * MT + b * N_ + vcol];

    // cooperative infl staging: 256 thr = 32 rows x 8 thr; 8 floats each
    const int irow = tid >> 3, icol = (tid & 7) * 8;
    const float* ibase = &infl[((long)(b * N_ + q0 + irow)) * N_ + icol];

    fx4 o00 = {0,0,0,0}, o01 = {0,0,0,0}, o10 = {0,0,0,0}, o11 = {0,0,0,0};
    float l0 = 0.f, l1 = 0.f;
    const fx4 zero = {0,0,0,0};
    fx4 st[2][4];   // [qs][kt], compile-time indices only

    // transform+pack one 8-float strip into ab_lds[buf] (bf16 a'|b pairs)
    auto stage_ab = [&](int buf, float4 x0, float4 x1) {
        float xs[8] = {x0.x, x0.y, x0.z, x0.w, x1.x, x1.y, x1.z, x1.w};
        unsigned int u[8];
#pragma unroll
        for (int i = 0; i < 8; i++) {
            float a = fmaf(xs[i], iw1e, ib1e);
            float bb = fmaf(xs[i], iw2, ib2);
            u[i] = cvt_pk_bf16(a, bb);
        }
        uint4 lo = {u[0], u[1], u[2], u[3]};
        uint4 hi = {u[4], u[5], u[6], u[7]};
        *(uint4*)&ab_lds[buf][irow][icol]     = lo;
        *(uint4*)&ab_lds[buf][irow][icol + 4] = hi;
    };

    // ---------------- prologue: chunk 0 ----------------
    float4 i00 = *(const float4*)&ibase[0];
    float4 i01 = *(const float4*)&ibase[4];
    float4 fA0 = *(const float4*)&ibase[KC];
    float4 fA1 = *(const float4*)&ibase[KC + 4];
    bfx8 nk0 = *(const bfx8*)(kbase +  0L * E_);
    bfx8 nk1 = *(const bfx8*)(kbase + 16L * E_);
    bfx8 nk2 = *(const bfx8*)(kbase + 32L * E_);
    bfx8 nk3 = *(const bfx8*)(kbase + 48L * E_);
    bfx8 nv0 = *(const bfx8*)(vtg +  0L * MT);
    bfx8 nv1 = *(const bfx8*)(vtg +  8L * MT);
    bfx8 nv2 = *(const bfx8*)(vtg + 16L * MT);
    bfx8 nv3 = *(const bfx8*)(vtg + 24L * MT);
    stage_ab(0, i00, i01);
    __syncthreads();
    // QK(0)
    __builtin_amdgcn_s_setprio(1);
    st[0][0] = __builtin_amdgcn_mfma_f32_16x16x32_bf16(nk0, qf0, zero, 0, 0, 0);
    st[1][0] = __builtin_amdgcn_mfma_f32_16x16x32_bf16(nk0, qf1, zero, 0, 0, 0);
    st[0][1] = __builtin_amdgcn_mfma_f32_16x16x32_bf16(nk1, qf0, zero, 0, 0, 0);
    st[1][1] = __builtin_amdgcn_mfma_f32_16x16x32_bf16(nk1, qf1, zero, 0, 0, 0);
    st[0][2] = __builtin_amdgcn_mfma_f32_16x16x32_bf16(nk2, qf0, zero, 0, 0, 0);
    st[1][2] = __builtin_amdgcn_mfma_f32_16x16x32_bf16(nk2, qf1, zero, 0, 0, 0);
    st[0][3] = __builtin_amdgcn_mfma_f32_16x16x32_bf16(nk3, qf0, zero, 0, 0, 0);
    st[1][3] = __builtin_amdgcn_mfma_f32_16x16x32_bf16(nk3, qf1, zero, 0, 0, 0);
    __builtin_amdgcn_s_setprio(0);
    {   // V-stage(0): straight b128 copies, no VALU
        *(bfx8*)&vt_lds[h][vrow     ][vcol] = nv0;
        *(bfx8*)&vt_lds[h][vrow +  8][vcol] = nv1;
        *(bfx8*)&vt_lds[h][vrow + 16][vcol] = nv2;
        *(bfx8*)&vt_lds[h][vrow + 24][vcol] = nv3;
    }

    // ---------------- main loop ----------------
    for (int kk = 0; kk < N_; kk += KC) {
        const int cur = (kk >> 6) & 1, nxt = cur ^ 1;
        const int kn  = (kk +     KC) & (N_ - 1);
        const int kn2 = (kk + 2 * KC) & (N_ - 1);

        // issue next-chunk loads (V^T, K; infl 2 ahead)
        nv0 = *(const bfx8*)(vtg +  0L * MT + kn);
        nv1 = *(const bfx8*)(vtg +  8L * MT + kn);
        nv2 = *(const bfx8*)(vtg + 16L * MT + kn);
        nv3 = *(const bfx8*)(vtg + 24L * MT + kn);
        nk0 = *(const bfx8*)(kbase + (long)(kn +  0) * E_);
        nk1 = *(const bfx8*)(kbase + (long)(kn + 16) * E_);
        nk2 = *(const bfx8*)(kbase + (long)(kn + 32) * E_);
        nk3 = *(const bfx8*)(kbase + (long)(kn + 48) * E_);
        float4 fN0 = *(const float4*)&ibase[kn2];
        float4 fN1 = *(const float4*)&ibase[kn2 + 4];

        // transform+pack infl(kk+1) into buf[nxt] from regs loaded LAST body
        stage_ab(nxt, fA0, fA1);

        // softmax(kk): st + packed ab plane -> pr -> p_lds
#pragma unroll
        for (int qs = 0; qs < 2; qs++) {
#pragma unroll
            for (int t = 0; t < 4; t++) {
                uint4 u4 = *(const uint4*)&ab_lds[cur][qs * 16 + c][t * 16 + g4];
                unsigned int uu[4] = {u4.x, u4.y, u4.z, u4.w};
                float pr[4];
#pragma unroll
                for (int r = 0; r < 4; r++) {
                    float a  = __uint_as_float(uu[r] << 16);
                    float bb = __uint_as_float(uu[r] & 0xffff0000u);
                    float s = fmaf(st[qs][t][r], scale2, a);
                    float p = __builtin_amdgcn_exp2f(s);
                    if (qs == 0) l0 += p; else l1 += p;
                    pr[r] = p * bb;
                }
                unsigned int lo = cvt_pk_bf16(pr[0], pr[1]);
                unsigned int hi = cvt_pk_bf16(pr[2], pr[3]);
                *(uint2*)&p_lds[h][qs * 16 + c][t * 16 + g4] = make_uint2(lo, hi);
            }
        }

        // PV(kk)
        __builtin_amdgcn_s_setprio(1);
#pragma unroll
        for (int kh = 0; kh < 2; kh++) {
            bfx8 vf0 = *(const bfx8*)&vt_lds[h][c][g * 8 + kh * 32];
            bfx8 vf1 = *(const bfx8*)&vt_lds[h][16 + c][g * 8 + kh * 32];
            bfx8 pf0 = *(const bfx8*)&p_lds[h][c][g * 8 + kh * 32];
            bfx8 pf1 = *(const bfx8*)&p_lds[h][16 + c][g * 8 + kh * 32];
            o00 = __builtin_amdgcn_mfma_f32_16x16x32_bf16(pf0, vf0, o00, 0, 0, 0);
            o01 = __builtin_amdgcn_mfma_f32_16x16x32_bf16(pf0, vf1, o01, 0, 0, 0);
            o10 = __builtin_amdgcn_mfma_f32_16x16x32_bf16(pf1, vf0, o10, 0, 0, 0);
            o11 = __builtin_amdgcn_mfma_f32_16x16x32_bf16(pf1, vf1, o11, 0, 0, 0);
        }
        __builtin_amdgcn_s_setprio(0);

        __syncthreads();   // buf[cur] reads done; buf[nxt] writes visible

        if (kk != N_ - KC) {
            // QK(kk+1): K issued one body ago
            __builtin_amdgcn_s_setprio(1);
            st[0][0] = __builtin_amdgcn_mfma_f32_16x16x32_bf16(nk0, qf0, zero, 0, 0, 0);
            st[1][0] = __builtin_amdgcn_mfma_f32_16x16x32_bf16(nk0, qf1, zero, 0, 0, 0);
            st[0][1] = __builtin_amdgcn_mfma_f32_16x16x32_bf16(nk1, qf0, zero, 0, 0, 0);
            st[1][1] = __builtin_amdgcn_mfma_f32_16x16x32_bf16(nk1, qf1, zero, 0, 0, 0);
            st[0][2] = __builtin_amdgcn_mfma_f32_16x16x32_bf16(nk2, qf0, zero, 0, 0, 0);
            st[1][2] = __builtin_amdgcn_mfma_f32_16x16x32_bf16(nk2, qf1, zero, 0, 0, 0);
            st[0][3] = __builtin_amdgcn_mfma_f32_16x16x32_bf16(nk3, qf0, zero, 0, 0, 0);
            st[1][3] = __builtin_amdgcn_mfma_f32_16x16x32_bf16(nk3, qf1, zero, 0, 0, 0);
            __builtin_amdgcn_s_setprio(0);
            // V-stage(kk+1): b128 copies
            *(bfx8*)&vt_lds[h][vrow     ][vcol] = nv0;
            *(bfx8*)&vt_lds[h][vrow +  8][vcol] = nv1;
            *(bfx8*)&vt_lds[h][vrow + 16][vcol] = nv2;
            *(bfx8*)&vt_lds[h][vrow + 24][vcol] = nv3;
        }
        fA0 = fN0; fA1 = fN1;
    }

    // ---------------- epilogue ----------------
    float l0r = l0;
    l0r += __shfl_xor(l0r, 16); l0r += __shfl_xor(l0r, 32);
    float l1r = l1;
    l1r += __shfl_xor(l1r, 16); l1r += __shfl_xor(l1r, 32);
#pragma unroll
    for (int r = 0; r < 4; r++) {
        int src = (lane & 48) | (g4 + r);
        float inv0 = 1.0f / __shfl(l0r, src, 64);
        float inv1 = 1.0f / __shfl(l1r, src, 64);
        long row0 = ((long)(b * N_ + q0 +      g4 + r)) * E_ + head * D_;
        long row1 = ((long)(b * N_ + q0 + 16 + g4 + r)) * E_ + head * D_;
        out[row0 + c]      = f2bf(o00[r] * inv0);
        out[row0 + 16 + c] = f2bf(o01[r] * inv0);
        out[row1 + c]      = f2bf(o10[r] * inv1);
        out[row1 + 16 + c] = f2bf(o11[r] * inv1);
    }
}

// ------------------------------- launch ---------------------------------------
extern "C" void kernel_launch(void* const* d_in, const int* in_sizes, int n_in,
                              void* d_out, int out_size, void* d_ws, size_t ws_size,
                              hipStream_t stream)
{
    (void)in_sizes; (void)n_in; (void)out_size; (void)ws_size;
    const float* x    = (const float*)d_in[0];
    const float* infl = (const float*)d_in[1];
    const float* Wq   = (const float*)d_in[2];
    const float* Wk   = (const float*)d_in[3];
    const float* Wv   = (const float*)d_in[4];
    const float* Wo   = (const float*)d_in[5];
    const float* bo   = (const float*)d_in[6];
    const float* iw1  = (const float*)d_in[7];
    const float* ib1  = (const float*)d_in[8];
    const float* iw2  = (const float*)d_in[9];
    const float* ib2  = (const float*)d_in[10];
    const float* W1   = (const float*)d_in[11];
    const float* b1   = (const float*)d_in[12];
    const float* W2   = (const float*)d_in[13];
    const float* b2   = (const float*)d_in[14];
    const float* g1   = (const float*)d_in[15];
    const float* be1  = (const float*)d_in[16];
    const float* g2   = (const float*)d_in[17];
    const float* be2  = (const float*)d_in[18];

    char* base = (char*)d_ws;
    unsigned short* hb  = (unsigned short*)base;                          // 4 MB (bf16 h)
    unsigned short* lnb = (unsigned short*)(base + (4  << 20));           // 4 MB
    unsigned short* qb  = (unsigned short*)(base + (8  << 20));           // 4 MB
    unsigned short* kb  = (unsigned short*)(base + (12 << 20));           // 4 MB
    unsigned short* vtb = (unsigned short*)(base + (16 << 20));           // 4 MB (V^T)
    unsigned short* wqt = (unsigned short*)(base + (20 << 20));           // 6x128KB
    unsigned short* wkt = wqt + 65536;
    unsigned short* wvt = wkt + 65536;
    unsigned short* wot = wvt + 65536;
    unsigned short* w1t = wot + 65536;
    unsigned short* w2t = w1t + 65536;

    dim3 gemm_grid(128, 4);

    prep_w<<<dim3(8, 8, 6), 256, 0, stream>>>(Wq, Wk, Wv, Wo, W1, W2,
                                              wqt, wkt, wvt, wot, w1t, w2t);
    // 1. ln1 = LN(x) -> bf16 (1 wave/row, 4 rows/block)
    ln_kernel<<<B_ * N_ / 4, 256, 0, stream>>>(x, g1, be1, lnb);
    // 2. q, k, V^T in ONE launch (z==2 writes transposed V directly)
    gemm_qkv<<<dim3(128, 4, 3), 256, 0, stream>>>(lnb, wqt, qb, wkt, kb, wvt, vtb);
    // 3. attention (bf16 out into lnb); 512 blocks, 2/CU
    attn_mfma<<<B_ * (N_ / QT) * 2, 256, 0, stream>>>(qb, kb, vtb, infl,
                                                      iw1, ib1, iw2, ib2, lnb);
    // 4. h = attn @ Wo + bo + x -> bf16
    gemm_mfma<<<gemm_grid, 256, 0, stream>>>(lnb, wot, bo, x, 0, hb, 0, 1);
    // 5. ln2 = LN(h) -> bf16 (bf16 input)
    ln_bf16<<<B_ * N_ / 4, 256, 0, stream>>>(hb, g2, be2, lnb);
    // 6. t = relu(ln2 @ W1 + b1) -> bf16 (reuse qb)
    gemm_mfma<<<gemm_grid, 256, 0, stream>>>(lnb, w1t, b1, nullptr, 0, qb, 1, 1);
    // 7. out = t @ W2 + b2 + h (bf16 resid, fp32 out)
    gemm_mfma<<<gemm_grid, 256, 0, stream>>>(qb, w2t, b2, hb, 1, (float*)d_out, 0, 0);
}

// Round 19
// 130.717 us; speedup vs baseline: 1.0476x; 1.0476x over previous
//
#include <hip/hip_runtime.h>
#include <hip/hip_bf16.h>

#define B_  4
#define N_  2048
#define E_  256
#define H_  8
#define D_  32
#define QT  32   // q-rows per block
#define KC  64   // keys per chunk
#define HPB 4    // heads per block
#define KS  2    // k-splits per (b,hg,q0)
#define VTP 72   // V^T row stride (ushorts): 144B
#define PP  72   // P row stride (ushorts)
#define IFP 68   // ab row stride (uints): 272B
#define LOG2E 1.4426950408889634f

typedef __attribute__((ext_vector_type(8))) short bfx8;
typedef __attribute__((ext_vector_type(4))) float fx4;

__device__ __forceinline__ unsigned short f2bf(float f) {
    unsigned int u = __float_as_uint(f);
    u += 0x7fffu + ((u >> 16) & 1u);   // round-to-nearest-even
    return (unsigned short)(u >> 16);
}

__device__ __forceinline__ float bf2f(unsigned short u) {
    return __uint_as_float((unsigned int)u << 16);
}

// pack two f32 -> two bf16 (RNE) in one VALU op: dst = bf16(lo) | bf16(hi)<<16
__device__ __forceinline__ unsigned int cvt_pk_bf16(float lo, float hi) {
    unsigned int r;
    asm("v_cvt_pk_bf16_f32 %0, %1, %2" : "=v"(r) : "v"(lo), "v"(hi));
    return r;
}

// ---------- prep: Wt[n][k] = bf16(W[k][n]) for 6 weight matrices ----------
__global__ __launch_bounds__(256) void prep_w(
    const float* Wa, const float* Wb, const float* Wc,
    const float* Wd, const float* We, const float* Wf,
    unsigned short* Oa, unsigned short* Ob, unsigned short* Oc,
    unsigned short* Od, unsigned short* Oe, unsigned short* Of)
{
    int z = blockIdx.z;
    const float* src = z == 0 ? Wa : z == 1 ? Wb : z == 2 ? Wc
                     : z == 3 ? Wd : z == 4 ? We : Wf;
    unsigned short* dst = z == 0 ? Oa : z == 1 ? Ob : z == 2 ? Oc
                        : z == 3 ? Od : z == 4 ? Oe : Of;
    __shared__ float t[32][33];
    int n0 = blockIdx.x * 32, k0 = blockIdx.y * 32;
    int tx = threadIdx.x & 31, ty = threadIdx.x >> 5;
#pragma unroll
    for (int i = 0; i < 4; i++)
        t[ty + i * 8][tx] = src[(k0 + ty + i * 8) * E_ + n0 + tx];
    __syncthreads();
#pragma unroll
    for (int i = 0; i < 4; i++)
        dst[(n0 + ty + i * 8) * E_ + k0 + tx] = f2bf(t[tx][ty + i * 8]);
}

// ---------- LayerNorm (fp32 in): ONE WAVE per row; 4 rows/block ----------
__global__ __launch_bounds__(256) void ln_kernel(const float* __restrict__ x,
                                                 const float* __restrict__ g,
                                                 const float* __restrict__ be,
                                                 unsigned short* __restrict__ out)
{
    const int w = threadIdx.x >> 6, lane = threadIdx.x & 63;
    const long row = (long)blockIdx.x * 4 + w;
    const float* xr = &x[row * E_];
    float4 v = *(const float4*)&xr[lane * 4];
    float s  = v.x + v.y + v.z + v.w;
    float s2 = v.x * v.x + v.y * v.y + v.z * v.z + v.w * v.w;
#pragma unroll
    for (int off = 32; off; off >>= 1) {
        s  += __shfl_xor(s,  off, 64);
        s2 += __shfl_xor(s2, off, 64);
    }
    float mu  = s * (1.0f / E_);
    float var = s2 * (1.0f / E_) - mu * mu;
    float rstd = rsqrtf(var + 1e-5f);
    float4 gg = *(const float4*)&g[lane * 4];
    float4 bb = *(const float4*)&be[lane * 4];
    float y0 = (v.x - mu) * rstd * gg.x + bb.x;
    float y1 = (v.y - mu) * rstd * gg.y + bb.y;
    float y2 = (v.z - mu) * rstd * gg.z + bb.z;
    float y3 = (v.w - mu) * rstd * gg.w + bb.w;
    uint2 o;
    o.x = cvt_pk_bf16(y0, y1);
    o.y = cvt_pk_bf16(y2, y3);
    *(uint2*)&out[row * E_ + lane * 4] = o;
}

// ---------- LayerNorm (bf16 in): ONE WAVE per row; 4 rows/block ----------
__global__ __launch_bounds__(256) void ln_bf16(const unsigned short* __restrict__ x,
                                               const float* __restrict__ g,
                                               const float* __restrict__ be,
                                               unsigned short* __restrict__ out)
{
    const int w = threadIdx.x >> 6, lane = threadIdx.x & 63;
    const long row = (long)blockIdx.x * 4 + w;
    uint2 u = *(const uint2*)&x[row * E_ + lane * 4];
    float v0 = __uint_as_float(u.x << 16);
    float v1 = __uint_as_float(u.x & 0xffff0000u);
    float v2 = __uint_as_float(u.y << 16);
    float v3 = __uint_as_float(u.y & 0xffff0000u);
    float s  = v0 + v1 + v2 + v3;
    float s2 = v0 * v0 + v1 * v1 + v2 * v2 + v3 * v3;
#pragma unroll
    for (int off = 32; off; off >>= 1) {
        s  += __shfl_xor(s,  off, 64);
        s2 += __shfl_xor(s2, off, 64);
    }
    float mu  = s * (1.0f / E_);
    float var = s2 * (1.0f / E_) - mu * mu;
    float rstd = rsqrtf(var + 1e-5f);
    float4 gg = *(const float4*)&g[lane * 4];
    float4 bb = *(const float4*)&be[lane * 4];
    float y0 = (v0 - mu) * rstd * gg.x + bb.x;
    float y1 = (v1 - mu) * rstd * gg.y + bb.y;
    float y2 = (v2 - mu) * rstd * gg.z + bb.z;
    float y3 = (v3 - mu) * rstd * gg.w + bb.w;
    uint2 o;
    o.x = cvt_pk_bf16(y0, y1);
    o.y = cvt_pk_bf16(y2, y3);
    *(uint2*)&out[row * E_ + lane * 4] = o;
}

// ---------- bf16 MFMA GEMM core (64x64 tile, K=256 strip in LDS) ----------
// (R16 version — best measured.) C[m][n] = sum_k A[m][k]*Wt[n][k]; rbf: bf16 resid.
__device__ __forceinline__ void gemm_core(
    const unsigned short* __restrict__ A,
    const unsigned short* __restrict__ Wt,
    const float* __restrict__ bias,
    const void* __restrict__ resid, int rbf,
    void* __restrict__ Cv, int relu, int obf, int m0, int n0, int ldC)
{
    __shared__ unsigned short As[64 * 264];
    __shared__ unsigned short Bs[64 * 264];
    int tid = threadIdx.x;

    {   // stage both 64x256 strips (contiguous rows), coalesced 16B/lane
        const unsigned short* Ab = A  + (long)m0 * E_;
        const unsigned short* Bb = Wt + (long)n0 * E_;
        bfx8 va[8], vb[8];
#pragma unroll
        for (int i = 0; i < 8; i++) va[i] = *(const bfx8*)&Ab[(i * 256 + tid) * 8];
#pragma unroll
        for (int i = 0; i < 8; i++) vb[i] = *(const bfx8*)&Bb[(i * 256 + tid) * 8];
#pragma unroll
        for (int i = 0; i < 8; i++) {
            int fo = i * 256 + tid;
            int row = fo >> 5, c8 = fo & 31;
            *(bfx8*)&As[row * 264 + c8 * 8] = va[i];
            *(bfx8*)&Bs[row * 264 + c8 * 8] = vb[i];
        }
    }
    __syncthreads();

    int lane = tid & 63, w = tid >> 6;
    int c = lane & 15, g = lane >> 4;
    int wm = (w >> 1) * 32, wn = (w & 1) * 32;
    fx4 acc[2][2] = {};

#pragma unroll
    for (int ks = 0; ks < 8; ks++) {
        bfx8 a0 = *(const bfx8*)&As[(wm + c)      * 264 + ks * 32 + g * 8];
        bfx8 a1 = *(const bfx8*)&As[(wm + 16 + c) * 264 + ks * 32 + g * 8];
        bfx8 b0 = *(const bfx8*)&Bs[(wn + c)      * 264 + ks * 32 + g * 8];
        bfx8 b1 = *(const bfx8*)&Bs[(wn + 16 + c) * 264 + ks * 32 + g * 8];
        acc[0][0] = __builtin_amdgcn_mfma_f32_16x16x32_bf16(a0, b0, acc[0][0], 0, 0, 0);
        acc[0][1] = __builtin_amdgcn_mfma_f32_16x16x32_bf16(a0, b1, acc[0][1], 0, 0, 0);
        acc[1][0] = __builtin_amdgcn_mfma_f32_16x16x32_bf16(a1, b0, acc[1][0], 0, 0, 0);
        acc[1][1] = __builtin_amdgcn_mfma_f32_16x16x32_bf16(a1, b1, acc[1][1], 0, 0, 0);
    }

#pragma unroll
    for (int fm = 0; fm < 2; fm++)
#pragma unroll
        for (int r = 0; r < 4; r++) {
            int m = m0 + wm + fm * 16 + g * 4 + r;
#pragma unroll
            for (int fn = 0; fn < 2; fn++) {
                int n = n0 + wn + fn * 16 + c;
                float o = acc[fm][fn][r];
                if (bias)  o += bias[n];
                if (relu)  o = fmaxf(o, 0.f);
                if (resid) {
                    float rv = rbf ? bf2f(((const unsigned short*)resid)[(long)m * ldC + n])
                                   : ((const float*)resid)[(long)m * ldC + n];
                    o += rv;
                }
                if (obf) ((unsigned short*)Cv)[(long)m * ldC + n] = f2bf(o);
                else     ((float*)Cv)[(long)m * ldC + n] = o;
            }
        }
}

__global__ __launch_bounds__(256, 2) void gemm_mfma(
    const unsigned short* __restrict__ A,
    const unsigned short* __restrict__ Wt,
    const float* __restrict__ bias,
    const void* __restrict__ resid, int rbf,
    void* __restrict__ Cv, int relu, int obf)
{
    gemm_core(A, Wt, bias, resid, rbf, Cv, relu, obf,
              blockIdx.x * 64, blockIdx.y * 64, E_);
}

// merged QKV. z==2 computes V^T: Vt[ch][tok] = sum_k Wvt[ch][k]*X[tok][k]
__global__ __launch_bounds__(256, 2) void gemm_qkv(
    const unsigned short* __restrict__ A,
    const unsigned short* __restrict__ Wq, unsigned short* __restrict__ qo,
    const unsigned short* __restrict__ Wk, unsigned short* __restrict__ ko,
    const unsigned short* __restrict__ Wv, unsigned short* __restrict__ vto)
{
    int z = blockIdx.z;
    if (z == 2) {
        gemm_core(Wv, A, nullptr, nullptr, 0, vto, 0, 1,
                  blockIdx.y * 64, blockIdx.x * 64, B_ * N_);
    } else {
        const unsigned short* Wt = z == 0 ? Wq : Wk;
        unsigned short*       Cv = z == 0 ? qo : ko;
        gemm_core(A, Wt, nullptr, nullptr, 0, Cv, 0, 1,
                  blockIdx.x * 64, blockIdx.y * 64, E_);
    }
}

// ---------- MFMA flash attention, K-SPLIT x2: partial o/l per half ----------
// R16 structure; each block handles 1024 keys (half). Fixed-max softmax means
// partials combine exactly: out = (o0+o1)/(l0+l1). Disjoint infl/K/V streams
// per half -> no traffic duplication. Grid 1024 -> 3 blocks/CU resident.
__global__ __launch_bounds__(256, 2) void attn_mfma(
    const unsigned short* __restrict__ q,
    const unsigned short* __restrict__ k,
    const unsigned short* __restrict__ vt,   // [E_][B_*N_] channel-major
    const float* __restrict__ infl,
    const float* __restrict__ iw1p, const float* __restrict__ ib1p,
    const float* __restrict__ iw2p, const float* __restrict__ ib2p,
    float* __restrict__ opart,               // [KS][B_*N_][E_] fp32
    float* __restrict__ lpart)               // [KS][B_][H_][N_] fp32
{
    const int bx  = blockIdx.x;                 // 1024 blocks
    const int xcd = bx & 7;
    const int b   = xcd >> 1;                   // batch
    const int hg  = (xcd & 1) * HPB;            // head-group base
    const int ks  = (bx >> 3) & 1;              // k-half
    const int q0  = (bx >> 4) * QT;
    const int kof = ks * (N_ / 2);
    const int NH  = N_ / 2;                     // 1024 keys per block
    const int tid = threadIdx.x;
    const int h    = tid >> 6;                  // wave id 0..3
    const int head = hg + h;
    const int lane = tid & 63;
    const int c = lane & 15, g = lane >> 4, g4 = g * 4;

    const float iw1e = iw1p[0] * LOG2E, ib1e = ib1p[0] * LOG2E;
    const float iw2 = iw2p[0], ib2 = ib2p[0];
    const float scale2 = 0.17677669529663687f * LOG2E;  // log2e/sqrt(32)

    __shared__ unsigned short vt_lds[HPB][D_][VTP];     // 18432B wave-private
    __shared__ unsigned short p_lds[HPB][QT][PP];       // 18432B wave-private
    __shared__ unsigned int ab_lds[2][QT][IFP];         // 17408B block dbuf

    // Q fragments (2 q-subtiles)
    bfx8 qf0 = *(const bfx8*)&q[((long)(b * N_ + q0 +      c)) * E_ + head * D_ + g * 8];
    bfx8 qf1 = *(const bfx8*)&q[((long)(b * N_ + q0 + 16 + c)) * E_ + head * D_ + g * 8];

    const unsigned short* kbase = &k[((long)(b * N_) + c) * E_ + head * D_ + g * 8];
    // V^T staging coords: row = (lane>>3)+8i (d-channel), keys = (lane&7)*8
    const long MT = (long)B_ * N_;   // 8192
    const int vrow = lane >> 3, vcol = (lane & 7) * 8;
    const unsigned short* vtg = &vt[((long)(head * D_ + vrow)) * MT + b * N_ + vcol];

    // cooperative infl staging: 256 thr = 32 rows x 8 thr; 8 floats each
    const int irow = tid >> 3, icol = (tid & 7) * 8;
    const float* ibase = &infl[((long)(b * N_ + q0 + irow)) * N_ + icol];

    fx4 o00 = {0,0,0,0}, o01 = {0,0,0,0}, o10 = {0,0,0,0}, o11 = {0,0,0,0};
    float l0 = 0.f, l1 = 0.f;
    const fx4 zero = {0,0,0,0};
    fx4 st[2][4];   // [qs][kt], compile-time indices only

    // transform+pack one 8-float strip into ab_lds[buf] (bf16 a'|b pairs)
    auto stage_ab = [&](int buf, float4 x0, float4 x1) {
        float xs[8] = {x0.x, x0.y, x0.z, x0.w, x1.x, x1.y, x1.z, x1.w};
        unsigned int u[8];
#pragma unroll
        for (int i = 0; i < 8; i++) {
            float a = fmaf(xs[i], iw1e, ib1e);
            float bb = fmaf(xs[i], iw2, ib2);
            u[i] = cvt_pk_bf16(a, bb);
        }
        uint4 lo = {u[0], u[1], u[2], u[3]};
        uint4 hi = {u[4], u[5], u[6], u[7]};
        *(uint4*)&ab_lds[buf][irow][icol]     = lo;
        *(uint4*)&ab_lds[buf][irow][icol + 4] = hi;
    };

    // ---------------- prologue: chunk 0 of this half ----------------
    float4 i00 = *(const float4*)&ibase[kof];
    float4 i01 = *(const float4*)&ibase[kof + 4];
    float4 fA0 = *(const float4*)&ibase[kof + KC];
    float4 fA1 = *(const float4*)&ibase[kof + KC + 4];
    bfx8 nk0 = *(const bfx8*)(kbase + (long)(kof +  0) * E_);
    bfx8 nk1 = *(const bfx8*)(kbase + (long)(kof + 16) * E_);
    bfx8 nk2 = *(const bfx8*)(kbase + (long)(kof + 32) * E_);
    bfx8 nk3 = *(const bfx8*)(kbase + (long)(kof + 48) * E_);
    bfx8 nv0 = *(const bfx8*)(vtg +  0L * MT + kof);
    bfx8 nv1 = *(const bfx8*)(vtg +  8L * MT + kof);
    bfx8 nv2 = *(const bfx8*)(vtg + 16L * MT + kof);
    bfx8 nv3 = *(const bfx8*)(vtg + 24L * MT + kof);
    stage_ab(0, i00, i01);
    __syncthreads();
    // QK(0)
    __builtin_amdgcn_s_setprio(1);
    st[0][0] = __builtin_amdgcn_mfma_f32_16x16x32_bf16(nk0, qf0, zero, 0, 0, 0);
    st[1][0] = __builtin_amdgcn_mfma_f32_16x16x32_bf16(nk0, qf1, zero, 0, 0, 0);
    st[0][1] = __builtin_amdgcn_mfma_f32_16x16x32_bf16(nk1, qf0, zero, 0, 0, 0);
    st[1][1] = __builtin_amdgcn_mfma_f32_16x16x32_bf16(nk1, qf1, zero, 0, 0, 0);
    st[0][2] = __builtin_amdgcn_mfma_f32_16x16x32_bf16(nk2, qf0, zero, 0, 0, 0);
    st[1][2] = __builtin_amdgcn_mfma_f32_16x16x32_bf16(nk2, qf1, zero, 0, 0, 0);
    st[0][3] = __builtin_amdgcn_mfma_f32_16x16x32_bf16(nk3, qf0, zero, 0, 0, 0);
    st[1][3] = __builtin_amdgcn_mfma_f32_16x16x32_bf16(nk3, qf1, zero, 0, 0, 0);
    __builtin_amdgcn_s_setprio(0);
    {   // V-stage(0): straight b128 copies, no VALU
        *(bfx8*)&vt_lds[h][vrow     ][vcol] = nv0;
        *(bfx8*)&vt_lds[h][vrow +  8][vcol] = nv1;
        *(bfx8*)&vt_lds[h][vrow + 16][vcol] = nv2;
        *(bfx8*)&vt_lds[h][vrow + 24][vcol] = nv3;
    }

    // ---------------- main loop (16 chunks) ----------------
    for (int kk = 0; kk < NH; kk += KC) {
        const int cur = (kk >> 6) & 1, nxt = cur ^ 1;
        const int kn  = kof + ((kk +     KC) & (NH - 1));
        const int kn2 = kof + ((kk + 2 * KC) & (NH - 1));

        // issue next-chunk loads (V^T, K; infl 2 ahead)
        nv0 = *(const bfx8*)(vtg +  0L * MT + kn);
        nv1 = *(const bfx8*)(vtg +  8L * MT + kn);
        nv2 = *(const bfx8*)(vtg + 16L * MT + kn);
        nv3 = *(const bfx8*)(vtg + 24L * MT + kn);
        nk0 = *(const bfx8*)(kbase + (long)(kn +  0) * E_);
        nk1 = *(const bfx8*)(kbase + (long)(kn + 16) * E_);
        nk2 = *(const bfx8*)(kbase + (long)(kn + 32) * E_);
        nk3 = *(const bfx8*)(kbase + (long)(kn + 48) * E_);
        float4 fN0 = *(const float4*)&ibase[kn2];
        float4 fN1 = *(const float4*)&ibase[kn2 + 4];

        // transform+pack infl(kk+1) into buf[nxt] from regs loaded LAST body
        stage_ab(nxt, fA0, fA1);

        // softmax(kk): st + packed ab plane -> pr -> p_lds
#pragma unroll
        for (int qs = 0; qs < 2; qs++) {
#pragma unroll
            for (int t = 0; t < 4; t++) {
                uint4 u4 = *(const uint4*)&ab_lds[cur][qs * 16 + c][t * 16 + g4];
                unsigned int uu[4] = {u4.x, u4.y, u4.z, u4.w};
                float pr[4];
#pragma unroll
                for (int r = 0; r < 4; r++) {
                    float a  = __uint_as_float(uu[r] << 16);
                    float bb = __uint_as_float(uu[r] & 0xffff0000u);
                    float s = fmaf(st[qs][t][r], scale2, a);
                    float p = __builtin_amdgcn_exp2f(s);
                    if (qs == 0) l0 += p; else l1 += p;
                    pr[r] = p * bb;
                }
                unsigned int lo = cvt_pk_bf16(pr[0], pr[1]);
                unsigned int hi = cvt_pk_bf16(pr[2], pr[3]);
                *(uint2*)&p_lds[h][qs * 16 + c][t * 16 + g4] = make_uint2(lo, hi);
            }
        }

        // PV(kk)
        __builtin_amdgcn_s_setprio(1);
#pragma unroll
        for (int kh = 0; kh < 2; kh++) {
            bfx8 vf0 = *(const bfx8*)&vt_lds[h][c][g * 8 + kh * 32];
            bfx8 vf1 = *(const bfx8*)&vt_lds[h][16 + c][g * 8 + kh * 32];
            bfx8 pf0 = *(const bfx8*)&p_lds[h][c][g * 8 + kh * 32];
            bfx8 pf1 = *(const bfx8*)&p_lds[h][16 + c][g * 8 + kh * 32];
            o00 = __builtin_amdgcn_mfma_f32_16x16x32_bf16(pf0, vf0, o00, 0, 0, 0);
            o01 = __builtin_amdgcn_mfma_f32_16x16x32_bf16(pf0, vf1, o01, 0, 0, 0);
            o10 = __builtin_amdgcn_mfma_f32_16x16x32_bf16(pf1, vf0, o10, 0, 0, 0);
            o11 = __builtin_amdgcn_mfma_f32_16x16x32_bf16(pf1, vf1, o11, 0, 0, 0);
        }
        __builtin_amdgcn_s_setprio(0);

        __syncthreads();   // buf[cur] reads done; buf[nxt] writes visible

        if (kk != NH - KC) {
            // QK(kk+1): K issued one body ago
            __builtin_amdgcn_s_setprio(1);
            st[0][0] = __builtin_amdgcn_mfma_f32_16x16x32_bf16(nk0, qf0, zero, 0, 0, 0);
            st[1][0] = __builtin_amdgcn_mfma_f32_16x16x32_bf16(nk0, qf1, zero, 0, 0, 0);
            st[0][1] = __builtin_amdgcn_mfma_f32_16x16x32_bf16(nk1, qf0, zero, 0, 0, 0);
            st[1][1] = __builtin_amdgcn_mfma_f32_16x16x32_bf16(nk1, qf1, zero, 0, 0, 0);
            st[0][2] = __builtin_amdgcn_mfma_f32_16x16x32_bf16(nk2, qf0, zero, 0, 0, 0);
            st[1][2] = __builtin_amdgcn_mfma_f32_16x16x32_bf16(nk2, qf1, zero, 0, 0, 0);
            st[0][3] = __builtin_amdgcn_mfma_f32_16x16x32_bf16(nk3, qf0, zero, 0, 0, 0);
            st[1][3] = __builtin_amdgcn_mfma_f32_16x16x32_bf16(nk3, qf1, zero, 0, 0, 0);
            __builtin_amdgcn_s_setprio(0);
            // V-stage(kk+1): b128 copies
            *(bfx8*)&vt_lds[h][vrow     ][vcol] = nv0;
            *(bfx8*)&vt_lds[h][vrow +  8][vcol] = nv1;
            *(bfx8*)&vt_lds[h][vrow + 16][vcol] = nv2;
            *(bfx8*)&vt_lds[h][vrow + 24][vcol] = nv3;
        }
        fA0 = fN0; fA1 = fN1;
    }

    // ---------------- epilogue: write partials (no divide) ----------------
    float l0r = l0;
    l0r += __shfl_xor(l0r, 16); l0r += __shfl_xor(l0r, 32);
    float l1r = l1;
    l1r += __shfl_xor(l1r, 16); l1r += __shfl_xor(l1r, 32);
    const long SZ = (long)B_ * N_ * E_;
    float* op = opart + (long)ks * SZ;
#pragma unroll
    for (int r = 0; r < 4; r++) {
        long row0 = ((long)(b * N_ + q0 +      g4 + r)) * E_ + head * D_;
        long row1 = ((long)(b * N_ + q0 + 16 + g4 + r)) * E_ + head * D_;
        op[row0 + c]      = o00[r];
        op[row0 + 16 + c] = o01[r];
        op[row1 + c]      = o10[r];
        op[row1 + 16 + c] = o11[r];
    }
    if (g == 0) {   // lanes 0..15: row sums complete after reduce
        long lb = (((long)ks * B_ + b) * H_ + head) * N_ + q0;
        lpart[lb + c]      = l0r;
        lpart[lb + 16 + c] = l1r;
    }
}

// ---------- combine: out = (o0+o1)/(l0+l1), bf16 out ----------
__global__ __launch_bounds__(256) void attn_combine(
    const float* __restrict__ opart, const float* __restrict__ lpart,
    unsigned short* __restrict__ out)
{
    const int w = threadIdx.x >> 6, lane = threadIdx.x & 63;
    const long row = (long)blockIdx.x * 4 + w;      // 0..8191
    const int b = (int)(row >> 11);
    const int n = (int)(row & (N_ - 1));
    const int d = lane * 4;
    const int h = d >> 5;
    const long SZ = (long)B_ * N_ * E_;
    float4 o0 = *(const float4*)&opart[row * E_ + d];
    float4 o1 = *(const float4*)&opart[SZ + row * E_ + d];
    float l = lpart[((long)(b * H_ + h)) * N_ + n]
            + lpart[((long)((B_ + b) * H_ + h)) * N_ + n];
    float inv = 1.0f / l;
    uint2 o;
    o.x = cvt_pk_bf16((o0.x + o1.x) * inv, (o0.y + o1.y) * inv);
    o.y = cvt_pk_bf16((o0.z + o1.z) * inv, (o0.w + o1.w) * inv);
    *(uint2*)&out[row * E_ + d] = o;
}

// ------------------------------- launch ---------------------------------------
extern "C" void kernel_launch(void* const* d_in, const int* in_sizes, int n_in,
                              void* d_out, int out_size, void* d_ws, size_t ws_size,
                              hipStream_t stream)
{
    (void)in_sizes; (void)n_in; (void)out_size; (void)ws_size;
    const float* x    = (const float*)d_in[0];
    const float* infl = (const float*)d_in[1];
    const float* Wq   = (const float*)d_in[2];
    const float* Wk   = (const float*)d_in[3];
    const float* Wv   = (const float*)d_in[4];
    const float* Wo   = (const float*)d_in[5];
    const float* bo   = (const float*)d_in[6];
    const float* iw1  = (const float*)d_in[7];
    const float* ib1  = (const float*)d_in[8];
    const float* iw2  = (const float*)d_in[9];
    const float* ib2  = (const float*)d_in[10];
    const float* W1   = (const float*)d_in[11];
    const float* b1   = (const float*)d_in[12];
    const float* W2   = (const float*)d_in[13];
    const float* b2   = (const float*)d_in[14];
    const float* g1   = (const float*)d_in[15];
    const float* be1  = (const float*)d_in[16];
    const float* g2   = (const float*)d_in[17];
    const float* be2  = (const float*)d_in[18];

    char* base = (char*)d_ws;
    unsigned short* hb  = (unsigned short*)base;                          // 4 MB (bf16 h)
    unsigned short* lnb = (unsigned short*)(base + (4  << 20));           // 4 MB
    unsigned short* qb  = (unsigned short*)(base + (8  << 20));           // 4 MB
    unsigned short* kb  = (unsigned short*)(base + (12 << 20));           // 4 MB
    unsigned short* vtb = (unsigned short*)(base + (16 << 20));           // 4 MB (V^T)
    unsigned short* wqt = (unsigned short*)(base + (20 << 20));           // 6x128KB
    unsigned short* wkt = wqt + 65536;
    unsigned short* wvt = wkt + 65536;
    unsigned short* wot = wvt + 65536;
    unsigned short* w1t = wot + 65536;
    unsigned short* w2t = w1t + 65536;
    float* opart = (float*)(base + (21 << 20));                           // 16 MB
    float* lpart = (float*)(base + (37 << 20));                           // 512 KB

    dim3 gemm_grid(128, 4);

    prep_w<<<dim3(8, 8, 6), 256, 0, stream>>>(Wq, Wk, Wv, Wo, W1, W2,
                                              wqt, wkt, wvt, wot, w1t, w2t);
    // 1. ln1 = LN(x) -> bf16 (1 wave/row, 4 rows/block)
    ln_kernel<<<B_ * N_ / 4, 256, 0, stream>>>(x, g1, be1, lnb);
    // 2. q, k, V^T in ONE launch (z==2 writes transposed V directly)
    gemm_qkv<<<dim3(128, 4, 3), 256, 0, stream>>>(lnb, wqt, qb, wkt, kb, wvt, vtb);
    // 3. attention, K-split x2 -> partials; 1024 blocks, 3/CU resident
    attn_mfma<<<B_ * (N_ / QT) * 2 * KS, 256, 0, stream>>>(qb, kb, vtb, infl,
                                        iw1, ib1, iw2, ib2, opart, lpart);
    // 3b. combine halves -> bf16 into lnb
    attn_combine<<<B_ * N_ / 4, 256, 0, stream>>>(opart, lpart, lnb);
    // 4. h = attn @ Wo + bo + x -> bf16
    gemm_mfma<<<gemm_grid, 256, 0, stream>>>(lnb, wot, bo, x, 0, hb, 0, 1);
    // 5. ln2 = LN(h) -> bf16 (bf16 input)
    ln_bf16<<<B_ * N_ / 4, 256, 0, stream>>>(hb, g2, be2, lnb);
    // 6. t = relu(ln2 @ W1 + b1) -> bf16 (reuse qb)
    gemm_mfma<<<gemm_grid, 256, 0, stream>>>(lnb, w1t, b1, nullptr, 0, qb, 1, 1);
    // 7. out = t @ W2 + b2 + h (bf16 resid, fp32 out)
    gemm_mfma<<<gemm_grid, 256, 0, stream>>>(qb, w2t, b2, hb, 1, (float*)d_out, 0, 0);
}

// Round 20
// 123.996 us; speedup vs baseline: 1.1044x; 1.0542x over previous
//
#include <hip/hip_runtime.h>
#include <hip/hip_bf16.h>

#define B_  4
#define N_  2048
#define E_  256
#define H_  8
#define D_  32
#define QT  32   // q-rows per block
#define KC  64   // keys per chunk
#define HPB 4    // heads per block
#define VTP 72   // V^T row stride (ushorts): 144B
#define PP  72   // P row stride (ushorts)
#define IFP 68   // ab row stride (uints): 272B
#define LOG2E 1.4426950408889634f

typedef __attribute__((ext_vector_type(8))) short bfx8;
typedef __attribute__((ext_vector_type(4))) float fx4;

__device__ __forceinline__ unsigned short f2bf(float f) {
    unsigned int u = __float_as_uint(f);
    u += 0x7fffu + ((u >> 16) & 1u);   // round-to-nearest-even
    return (unsigned short)(u >> 16);
}

__device__ __forceinline__ float bf2f(unsigned short u) {
    return __uint_as_float((unsigned int)u << 16);
}

// pack two f32 -> two bf16 (RNE) in one VALU op: dst = bf16(lo) | bf16(hi)<<16
__device__ __forceinline__ unsigned int cvt_pk_bf16(float lo, float hi) {
    unsigned int r;
    asm("v_cvt_pk_bf16_f32 %0, %1, %2" : "=v"(r) : "v"(lo), "v"(hi));
    return r;
}

// ---------- prep: Wt[n][k] = bf16(W[k][n]) for 6 weight matrices ----------
__global__ __launch_bounds__(256) void prep_w(
    const float* Wa, const float* Wb, const float* Wc,
    const float* Wd, const float* We, const float* Wf,
    unsigned short* Oa, unsigned short* Ob, unsigned short* Oc,
    unsigned short* Od, unsigned short* Oe, unsigned short* Of)
{
    int z = blockIdx.z;
    const float* src = z == 0 ? Wa : z == 1 ? Wb : z == 2 ? Wc
                     : z == 3 ? Wd : z == 4 ? We : Wf;
    unsigned short* dst = z == 0 ? Oa : z == 1 ? Ob : z == 2 ? Oc
                        : z == 3 ? Od : z == 4 ? Oe : Of;
    __shared__ float t[32][33];
    int n0 = blockIdx.x * 32, k0 = blockIdx.y * 32;
    int tx = threadIdx.x & 31, ty = threadIdx.x >> 5;
#pragma unroll
    for (int i = 0; i < 4; i++)
        t[ty + i * 8][tx] = src[(k0 + ty + i * 8) * E_ + n0 + tx];
    __syncthreads();
#pragma unroll
    for (int i = 0; i < 4; i++)
        dst[(n0 + ty + i * 8) * E_ + k0 + tx] = f2bf(t[tx][ty + i * 8]);
}

// ---------- LayerNorm (fp32 in): ONE WAVE per row; 4 rows/block ----------
__global__ __launch_bounds__(256) void ln_kernel(const float* __restrict__ x,
                                                 const float* __restrict__ g,
                                                 const float* __restrict__ be,
                                                 unsigned short* __restrict__ out)
{
    const int w = threadIdx.x >> 6, lane = threadIdx.x & 63;
    const long row = (long)blockIdx.x * 4 + w;
    const float* xr = &x[row * E_];
    float4 v = *(const float4*)&xr[lane * 4];
    float s  = v.x + v.y + v.z + v.w;
    float s2 = v.x * v.x + v.y * v.y + v.z * v.z + v.w * v.w;
#pragma unroll
    for (int off = 32; off; off >>= 1) {
        s  += __shfl_xor(s,  off, 64);
        s2 += __shfl_xor(s2, off, 64);
    }
    float mu  = s * (1.0f / E_);
    float var = s2 * (1.0f / E_) - mu * mu;
    float rstd = rsqrtf(var + 1e-5f);
    float4 gg = *(const float4*)&g[lane * 4];
    float4 bb = *(const float4*)&be[lane * 4];
    float y0 = (v.x - mu) * rstd * gg.x + bb.x;
    float y1 = (v.y - mu) * rstd * gg.y + bb.y;
    float y2 = (v.z - mu) * rstd * gg.z + bb.z;
    float y3 = (v.w - mu) * rstd * gg.w + bb.w;
    uint2 o;
    o.x = cvt_pk_bf16(y0, y1);
    o.y = cvt_pk_bf16(y2, y3);
    *(uint2*)&out[row * E_ + lane * 4] = o;
}

// ---------- LayerNorm (bf16 in): ONE WAVE per row; 4 rows/block ----------
__global__ __launch_bounds__(256) void ln_bf16(const unsigned short* __restrict__ x,
                                               const float* __restrict__ g,
                                               const float* __restrict__ be,
                                               unsigned short* __restrict__ out)
{
    const int w = threadIdx.x >> 6, lane = threadIdx.x & 63;
    const long row = (long)blockIdx.x * 4 + w;
    uint2 u = *(const uint2*)&x[row * E_ + lane * 4];
    float v0 = __uint_as_float(u.x << 16);
    float v1 = __uint_as_float(u.x & 0xffff0000u);
    float v2 = __uint_as_float(u.y << 16);
    float v3 = __uint_as_float(u.y & 0xffff0000u);
    float s  = v0 + v1 + v2 + v3;
    float s2 = v0 * v0 + v1 * v1 + v2 * v2 + v3 * v3;
#pragma unroll
    for (int off = 32; off; off >>= 1) {
        s  += __shfl_xor(s,  off, 64);
        s2 += __shfl_xor(s2, off, 64);
    }
    float mu  = s * (1.0f / E_);
    float var = s2 * (1.0f / E_) - mu * mu;
    float rstd = rsqrtf(var + 1e-5f);
    float4 gg = *(const float4*)&g[lane * 4];
    float4 bb = *(const float4*)&be[lane * 4];
    float y0 = (v0 - mu) * rstd * gg.x + bb.x;
    float y1 = (v1 - mu) * rstd * gg.y + bb.y;
    float y2 = (v2 - mu) * rstd * gg.z + bb.z;
    float y3 = (v3 - mu) * rstd * gg.w + bb.w;
    uint2 o;
    o.x = cvt_pk_bf16(y0, y1);
    o.y = cvt_pk_bf16(y2, y3);
    *(uint2*)&out[row * E_ + lane * 4] = o;
}

// ---------- bf16 MFMA GEMM core (64x64 tile, K=256 strip in LDS) ----------
// C[m][n] = sum_k A[m][k] * Wt[n][k]; C stride = ldC. rbf: residual is bf16.
__device__ __forceinline__ void gemm_core(
    const unsigned short* __restrict__ A,
    const unsigned short* __restrict__ Wt,
    const float* __restrict__ bias,
    const void* __restrict__ resid, int rbf,
    void* __restrict__ Cv, int relu, int obf, int m0, int n0, int ldC)
{
    __shared__ unsigned short As[64 * 264];
    __shared__ unsigned short Bs[64 * 264];
    int tid = threadIdx.x;

    {   // stage both 64x256 strips (contiguous rows), coalesced 16B/lane
        const unsigned short* Ab = A  + (long)m0 * E_;
        const unsigned short* Bb = Wt + (long)n0 * E_;
        bfx8 va[8], vb[8];
#pragma unroll
        for (int i = 0; i < 8; i++) va[i] = *(const bfx8*)&Ab[(i * 256 + tid) * 8];
#pragma unroll
        for (int i = 0; i < 8; i++) vb[i] = *(const bfx8*)&Bb[(i * 256 + tid) * 8];
#pragma unroll
        for (int i = 0; i < 8; i++) {
            int fo = i * 256 + tid;
            int row = fo >> 5, c8 = fo & 31;
            *(bfx8*)&As[row * 264 + c8 * 8] = va[i];
            *(bfx8*)&Bs[row * 264 + c8 * 8] = vb[i];
        }
    }
    __syncthreads();

    int lane = tid & 63, w = tid >> 6;
    int c = lane & 15, g = lane >> 4;
    int wm = (w >> 1) * 32, wn = (w & 1) * 32;
    fx4 acc[2][2] = {};

#pragma unroll
    for (int ks = 0; ks < 8; ks++) {
        bfx8 a0 = *(const bfx8*)&As[(wm + c)      * 264 + ks * 32 + g * 8];
        bfx8 a1 = *(const bfx8*)&As[(wm + 16 + c) * 264 + ks * 32 + g * 8];
        bfx8 b0 = *(const bfx8*)&Bs[(wn + c)      * 264 + ks * 32 + g * 8];
        bfx8 b1 = *(const bfx8*)&Bs[(wn + 16 + c) * 264 + ks * 32 + g * 8];
        acc[0][0] = __builtin_amdgcn_mfma_f32_16x16x32_bf16(a0, b0, acc[0][0], 0, 0, 0);
        acc[0][1] = __builtin_amdgcn_mfma_f32_16x16x32_bf16(a0, b1, acc[0][1], 0, 0, 0);
        acc[1][0] = __builtin_amdgcn_mfma_f32_16x16x32_bf16(a1, b0, acc[1][0], 0, 0, 0);
        acc[1][1] = __builtin_amdgcn_mfma_f32_16x16x32_bf16(a1, b1, acc[1][1], 0, 0, 0);
    }

#pragma unroll
    for (int fm = 0; fm < 2; fm++)
#pragma unroll
        for (int r = 0; r < 4; r++) {
            int m = m0 + wm + fm * 16 + g * 4 + r;
#pragma unroll
            for (int fn = 0; fn < 2; fn++) {
                int n = n0 + wn + fn * 16 + c;
                float o = acc[fm][fn][r];
                if (bias)  o += bias[n];
                if (relu)  o = fmaxf(o, 0.f);
                if (resid) {
                    float rv = rbf ? bf2f(((const unsigned short*)resid)[(long)m * ldC + n])
                                   : ((const float*)resid)[(long)m * ldC + n];
                    o += rv;
                }
                if (obf) ((unsigned short*)Cv)[(long)m * ldC + n] = f2bf(o);
                else     ((float*)Cv)[(long)m * ldC + n] = o;
            }
        }
}

__global__ __launch_bounds__(256, 2) void gemm_mfma(
    const unsigned short* __restrict__ A,
    const unsigned short* __restrict__ Wt,
    const float* __restrict__ bias,
    const void* __restrict__ resid, int rbf,
    void* __restrict__ Cv, int relu, int obf)
{
    gemm_core(A, Wt, bias, resid, rbf, Cv, relu, obf,
              blockIdx.x * 64, blockIdx.y * 64, E_);
}

// merged QKV. z==2 computes V^T: Vt[ch][tok] = sum_k Wvt[ch][k]*X[tok][k]
// (roles of A/W swapped; channel-major output, ldC = 8192).
__global__ __launch_bounds__(256, 2) void gemm_qkv(
    const unsigned short* __restrict__ A,
    const unsigned short* __restrict__ Wq, unsigned short* __restrict__ qo,
    const unsigned short* __restrict__ Wk, unsigned short* __restrict__ ko,
    const unsigned short* __restrict__ Wv, unsigned short* __restrict__ vto)
{
    int z = blockIdx.z;
    if (z == 2) {
        gemm_core(Wv, A, nullptr, nullptr, 0, vto, 0, 1,
                  blockIdx.y * 64, blockIdx.x * 64, B_ * N_);
    } else {
        const unsigned short* Wt = z == 0 ? Wq : Wk;
        unsigned short*       Cv = z == 0 ? qo : ko;
        gemm_core(A, Wt, nullptr, nullptr, 0, Cv, 0, 1,
                  blockIdx.x * 64, blockIdx.y * 64, E_);
    }
}

// ---------- MFMA flash attention: QT=32, 4 heads/block, dbuf infl ------------
// (R16 config — best measured 124.6us.) ab plane: uint = bf16(a')|bf16(b)<<16
//   a' = fr*iw1*log2e + ib1*log2e  (dropped -M2 constant cancels exactly)
//   b  = fr*iw2 + ib2
// softmax: s = fma(st, scale2, a'); p = exp2(s); pr = p*b. uint4 reads (16B).
__global__ __launch_bounds__(256, 2) void attn_mfma(
    const unsigned short* __restrict__ q,
    const unsigned short* __restrict__ k,
    const unsigned short* __restrict__ vt,   // [E_][B_*N_] channel-major
    const float* __restrict__ infl,
    const float* __restrict__ iw1p, const float* __restrict__ ib1p,
    const float* __restrict__ iw2p, const float* __restrict__ ib2p,
    unsigned short* __restrict__ out)
{
    const int bx  = blockIdx.x;                 // 512 blocks
    const int xcd = bx & 7;
    const int b   = xcd >> 1;                   // batch
    const int hg  = (xcd & 1) * HPB;            // head-group base
    const int q0  = (bx >> 3) * QT;
    const int tid = threadIdx.x;
    const int h    = tid >> 6;                  // wave id 0..3
    const int head = hg + h;
    const int lane = tid & 63;
    const int c = lane & 15, g = lane >> 4, g4 = g * 4;

    const float iw1e = iw1p[0] * LOG2E, ib1e = ib1p[0] * LOG2E;
    const float iw2 = iw2p[0], ib2 = ib2p[0];
    const float scale2 = 0.17677669529663687f * LOG2E;  // log2e/sqrt(32)

    __shared__ unsigned short vt_lds[HPB][D_][VTP];     // 18432B wave-private
    __shared__ unsigned short p_lds[HPB][QT][PP];       // 18432B wave-private
    __shared__ unsigned int ab_lds[2][QT][IFP];         // 17408B block dbuf

    // Q fragments (2 q-subtiles)
    bfx8 qf0 = *(const bfx8*)&q[((long)(b * N_ + q0 +      c)) * E_ + head * D_ + g * 8];
    bfx8 qf1 = *(const bfx8*)&q[((long)(b * N_ + q0 + 16 + c)) * E_ + head * D_ + g * 8];

    const unsigned short* kbase = &k[((long)(b * N_) + c) * E_ + head * D_ + g * 8];
    // V^T staging coords: row = (lane>>3)+8i (d-channel), keys = (lane&7)*8
    const long MT = (long)B_ * N_;   // 8192
    const int vrow = lane >> 3, vcol = (lane & 7) * 8;
    const unsigned short* vtg = &vt[((long)(head * D_ + vrow)) * MT + b * N_ + vcol];

    // cooperative infl staging: 256 thr = 32 rows x 8 thr; 8 floats each
    const int irow = tid >> 3, icol = (tid & 7) * 8;
    const float* ibase = &infl[((long)(b * N_ + q0 + irow)) * N_ + icol];

    fx4 o00 = {0,0,0,0}, o01 = {0,0,0,0}, o10 = {0,0,0,0}, o11 = {0,0,0,0};
    float l0 = 0.f, l1 = 0.f;
    const fx4 zero = {0,0,0,0};
    fx4 st[2][4];   // [qs][kt], compile-time indices only

    // transform+pack one 8-float strip into ab_lds[buf] (bf16 a'|b pairs)
    auto stage_ab = [&](int buf, float4 x0, float4 x1) {
        float xs[8] = {x0.x, x0.y, x0.z, x0.w, x1.x, x1.y, x1.z, x1.w};
        unsigned int u[8];
#pragma unroll
        for (int i = 0; i < 8; i++) {
            float a = fmaf(xs[i], iw1e, ib1e);
            float bb = fmaf(xs[i], iw2, ib2);
            u[i] = cvt_pk_bf16(a, bb);
        }
        uint4 lo = {u[0], u[1], u[2], u[3]};
        uint4 hi = {u[4], u[5], u[6], u[7]};
        *(uint4*)&ab_lds[buf][irow][icol]     = lo;
        *(uint4*)&ab_lds[buf][irow][icol + 4] = hi;
    };

    // ---------------- prologue: chunk 0 ----------------
    float4 i00 = *(const float4*)&ibase[0];
    float4 i01 = *(const float4*)&ibase[4];
    float4 fA0 = *(const float4*)&ibase[KC];
    float4 fA1 = *(const float4*)&ibase[KC + 4];
    bfx8 nk0 = *(const bfx8*)(kbase +  0L * E_);
    bfx8 nk1 = *(const bfx8*)(kbase + 16L * E_);
    bfx8 nk2 = *(const bfx8*)(kbase + 32L * E_);
    bfx8 nk3 = *(const bfx8*)(kbase + 48L * E_);
    bfx8 nv0 = *(const bfx8*)(vtg +  0L * MT);
    bfx8 nv1 = *(const bfx8*)(vtg +  8L * MT);
    bfx8 nv2 = *(const bfx8*)(vtg + 16L * MT);
    bfx8 nv3 = *(const bfx8*)(vtg + 24L * MT);
    stage_ab(0, i00, i01);
    __syncthreads();
    // QK(0)
    __builtin_amdgcn_s_setprio(1);
    st[0][0] = __builtin_amdgcn_mfma_f32_16x16x32_bf16(nk0, qf0, zero, 0, 0, 0);
    st[1][0] = __builtin_amdgcn_mfma_f32_16x16x32_bf16(nk0, qf1, zero, 0, 0, 0);
    st[0][1] = __builtin_amdgcn_mfma_f32_16x16x32_bf16(nk1, qf0, zero, 0, 0, 0);
    st[1][1] = __builtin_amdgcn_mfma_f32_16x16x32_bf16(nk1, qf1, zero, 0, 0, 0);
    st[0][2] = __builtin_amdgcn_mfma_f32_16x16x32_bf16(nk2, qf0, zero, 0, 0, 0);
    st[1][2] = __builtin_amdgcn_mfma_f32_16x16x32_bf16(nk2, qf1, zero, 0, 0, 0);
    st[0][3] = __builtin_amdgcn_mfma_f32_16x16x32_bf16(nk3, qf0, zero, 0, 0, 0);
    st[1][3] = __builtin_amdgcn_mfma_f32_16x16x32_bf16(nk3, qf1, zero, 0, 0, 0);
    __builtin_amdgcn_s_setprio(0);
    {   // V-stage(0): straight b128 copies, no VALU
        *(bfx8*)&vt_lds[h][vrow     ][vcol] = nv0;
        *(bfx8*)&vt_lds[h][vrow +  8][vcol] = nv1;
        *(bfx8*)&vt_lds[h][vrow + 16][vcol] = nv2;
        *(bfx8*)&vt_lds[h][vrow + 24][vcol] = nv3;
    }

    // ---------------- main loop ----------------
    for (int kk = 0; kk < N_; kk += KC) {
        const int cur = (kk >> 6) & 1, nxt = cur ^ 1;
        const int kn  = (kk +     KC) & (N_ - 1);
        const int kn2 = (kk + 2 * KC) & (N_ - 1);

        // issue next-chunk loads (V^T, K; infl 2 ahead)
        nv0 = *(const bfx8*)(vtg +  0L * MT + kn);
        nv1 = *(const bfx8*)(vtg +  8L * MT + kn);
        nv2 = *(const bfx8*)(vtg + 16L * MT + kn);
        nv3 = *(const bfx8*)(vtg + 24L * MT + kn);
        nk0 = *(const bfx8*)(kbase + (long)(kn +  0) * E_);
        nk1 = *(const bfx8*)(kbase + (long)(kn + 16) * E_);
        nk2 = *(const bfx8*)(kbase + (long)(kn + 32) * E_);
        nk3 = *(const bfx8*)(kbase + (long)(kn + 48) * E_);
        float4 fN0 = *(const float4*)&ibase[kn2];
        float4 fN1 = *(const float4*)&ibase[kn2 + 4];

        // transform+pack infl(kk+1) into buf[nxt] from regs loaded LAST body
        stage_ab(nxt, fA0, fA1);

        // softmax(kk): st + packed ab plane -> pr -> p_lds
#pragma unroll
        for (int qs = 0; qs < 2; qs++) {
#pragma unroll
            for (int t = 0; t < 4; t++) {
                uint4 u4 = *(const uint4*)&ab_lds[cur][qs * 16 + c][t * 16 + g4];
                unsigned int uu[4] = {u4.x, u4.y, u4.z, u4.w};
                float pr[4];
#pragma unroll
                for (int r = 0; r < 4; r++) {
                    float a  = __uint_as_float(uu[r] << 16);
                    float bb = __uint_as_float(uu[r] & 0xffff0000u);
                    float s = fmaf(st[qs][t][r], scale2, a);
                    float p = __builtin_amdgcn_exp2f(s);
                    if (qs == 0) l0 += p; else l1 += p;
                    pr[r] = p * bb;
                }
                unsigned int lo = cvt_pk_bf16(pr[0], pr[1]);
                unsigned int hi = cvt_pk_bf16(pr[2], pr[3]);
                *(uint2*)&p_lds[h][qs * 16 + c][t * 16 + g4] = make_uint2(lo, hi);
            }
        }

        // PV(kk)
        __builtin_amdgcn_s_setprio(1);
#pragma unroll
        for (int kh = 0; kh < 2; kh++) {
            bfx8 vf0 = *(const bfx8*)&vt_lds[h][c][g * 8 + kh * 32];
            bfx8 vf1 = *(const bfx8*)&vt_lds[h][16 + c][g * 8 + kh * 32];
            bfx8 pf0 = *(const bfx8*)&p_lds[h][c][g * 8 + kh * 32];
            bfx8 pf1 = *(const bfx8*)&p_lds[h][16 + c][g * 8 + kh * 32];
            o00 = __builtin_amdgcn_mfma_f32_16x16x32_bf16(pf0, vf0, o00, 0, 0, 0);
            o01 = __builtin_amdgcn_mfma_f32_16x16x32_bf16(pf0, vf1, o01, 0, 0, 0);
            o10 = __builtin_amdgcn_mfma_f32_16x16x32_bf16(pf1, vf0, o10, 0, 0, 0);
            o11 = __builtin_amdgcn_mfma_f32_16x16x32_bf16(pf1, vf1, o11, 0, 0, 0);
        }
        __builtin_amdgcn_s_setprio(0);

        __syncthreads();   // buf[cur] reads done; buf[nxt] writes visible

        if (kk != N_ - KC) {
            // QK(kk+1): K issued one body ago
            __builtin_amdgcn_s_setprio(1);
            st[0][0] = __builtin_amdgcn_mfma_f32_16x16x32_bf16(nk0, qf0, zero, 0, 0, 0);
            st[1][0] = __builtin_amdgcn_mfma_f32_16x16x32_bf16(nk0, qf1, zero, 0, 0, 0);
            st[0][1] = __builtin_amdgcn_mfma_f32_16x16x32_bf16(nk1, qf0, zero, 0, 0, 0);
            st[1][1] = __builtin_amdgcn_mfma_f32_16x16x32_bf16(nk1, qf1, zero, 0, 0, 0);
            st[0][2] = __builtin_amdgcn_mfma_f32_16x16x32_bf16(nk2, qf0, zero, 0, 0, 0);
            st[1][2] = __builtin_amdgcn_mfma_f32_16x16x32_bf16(nk2, qf1, zero, 0, 0, 0);
            st[0][3] = __builtin_amdgcn_mfma_f32_16x16x32_bf16(nk3, qf0, zero, 0, 0, 0);
            st[1][3] = __builtin_amdgcn_mfma_f32_16x16x32_bf16(nk3, qf1, zero, 0, 0, 0);
            __builtin_amdgcn_s_setprio(0);
            // V-stage(kk+1): b128 copies
            *(bfx8*)&vt_lds[h][vrow     ][vcol] = nv0;
            *(bfx8*)&vt_lds[h][vrow +  8][vcol] = nv1;
            *(bfx8*)&vt_lds[h][vrow + 16][vcol] = nv2;
            *(bfx8*)&vt_lds[h][vrow + 24][vcol] = nv3;
        }
        fA0 = fN0; fA1 = fN1;
    }

    // ---------------- epilogue ----------------
    float l0r = l0;
    l0r += __shfl_xor(l0r, 16); l0r += __shfl_xor(l0r, 32);
    float l1r = l1;
    l1r += __shfl_xor(l1r, 16); l1r += __shfl_xor(l1r, 32);
#pragma unroll
    for (int r = 0; r < 4; r++) {
        int src = (lane & 48) | (g4 + r);
        float inv0 = 1.0f / __shfl(l0r, src, 64);
        float inv1 = 1.0f / __shfl(l1r, src, 64);
        long row0 = ((long)(b * N_ + q0 +      g4 + r)) * E_ + head * D_;
        long row1 = ((long)(b * N_ + q0 + 16 + g4 + r)) * E_ + head * D_;
        out[row0 + c]      = f2bf(o00[r] * inv0);
        out[row0 + 16 + c] = f2bf(o01[r] * inv0);
        out[row1 + c]      = f2bf(o10[r] * inv1);
        out[row1 + 16 + c] = f2bf(o11[r] * inv1);
    }
}

// ------------------------------- launch ---------------------------------------
extern "C" void kernel_launch(void* const* d_in, const int* in_sizes, int n_in,
                              void* d_out, int out_size, void* d_ws, size_t ws_size,
                              hipStream_t stream)
{
    (void)in_sizes; (void)n_in; (void)out_size; (void)ws_size;
    const float* x    = (const float*)d_in[0];
    const float* infl = (const float*)d_in[1];
    const float* Wq   = (const float*)d_in[2];
    const float* Wk   = (const float*)d_in[3];
    const float* Wv   = (const float*)d_in[4];
    const float* Wo   = (const float*)d_in[5];
    const float* bo   = (const float*)d_in[6];
    const float* iw1  = (const float*)d_in[7];
    const float* ib1  = (const float*)d_in[8];
    const float* iw2  = (const float*)d_in[9];
    const float* ib2  = (const float*)d_in[10];
    const float* W1   = (const float*)d_in[11];
    const float* b1   = (const float*)d_in[12];
    const float* W2   = (const float*)d_in[13];
    const float* b2   = (const float*)d_in[14];
    const float* g1   = (const float*)d_in[15];
    const float* be1  = (const float*)d_in[16];
    const float* g2   = (const float*)d_in[17];
    const float* be2  = (const float*)d_in[18];

    char* base = (char*)d_ws;
    unsigned short* hb  = (unsigned short*)base;                          // 4 MB (bf16 h)
    unsigned short* lnb = (unsigned short*)(base + (4  << 20));           // 4 MB
    unsigned short* qb  = (unsigned short*)(base + (8  << 20));           // 4 MB
    unsigned short* kb  = (unsigned short*)(base + (12 << 20));           // 4 MB
    unsigned short* vtb = (unsigned short*)(base + (16 << 20));           // 4 MB (V^T)
    unsigned short* wqt = (unsigned short*)(base + (20 << 20));           // 6x128KB
    unsigned short* wkt = wqt + 65536;
    unsigned short* wvt = wkt + 65536;
    unsigned short* wot = wvt + 65536;
    unsigned short* w1t = wot + 65536;
    unsigned short* w2t = w1t + 65536;

    dim3 gemm_grid(128, 4);

    prep_w<<<dim3(8, 8, 6), 256, 0, stream>>>(Wq, Wk, Wv, Wo, W1, W2,
                                              wqt, wkt, wvt, wot, w1t, w2t);
    // 1. ln1 = LN(x) -> bf16 (1 wave/row, 4 rows/block)
    ln_kernel<<<B_ * N_ / 4, 256, 0, stream>>>(x, g1, be1, lnb);
    // 2. q, k, V^T in ONE launch (z==2 writes transposed V directly)
    gemm_qkv<<<dim3(128, 4, 3), 256, 0, stream>>>(lnb, wqt, qb, wkt, kb, wvt, vtb);
    // 3. attention (bf16 out into lnb); 512 blocks, 2/CU
    attn_mfma<<<B_ * (N_ / QT) * 2, 256, 0, stream>>>(qb, kb, vtb, infl,
                                                      iw1, ib1, iw2, ib2, lnb);
    // 4. h = attn @ Wo + bo + x -> bf16
    gemm_mfma<<<gemm_grid, 256, 0, stream>>>(lnb, wot, bo, x, 0, hb, 0, 1);
    // 5. ln2 = LN(h) -> bf16 (bf16 input)
    ln_bf16<<<B_ * N_ / 4, 256, 0, stream>>>(hb, g2, be2, lnb);
    // 6. t = relu(ln2 @ W1 + b1) -> bf16 (reuse qb)
    gemm_mfma<<<gemm_grid, 256, 0, stream>>>(lnb, w1t, b1, nullptr, 0, qb, 1, 1);
    // 7. out = t @ W2 + b2 + h (bf16 resid, fp32 out)
    gemm_mfma<<<gemm_grid, 256, 0, stream>>>(qb, w2t, b2, hb, 1, (float*)d_out, 0, 0);
}